// Round 1
// baseline (1298.790 us; speedup 1.0000x reference)
//
#include <hip/hip_runtime.h>
#include <math.h>

#define N_ROWS    8192
#define C_CLASSES 32000
#define BLOCK     256

// math.log(32000) in double, rounded to float
__device__ __constant__ float kTAU      = 10.3734911810494682f;
__device__ __constant__ float kNEG2oE   = -0.73575888234288464f;  // -2/e

__device__ inline float lambertw0f(float y) {
    // Principal-branch Lambert W via 12 Halley iterations (mirrors reference).
    const float e = 2.71828182845904523536f;
    float w;
    if (y < 0.0f) {
        w = -1.0f + sqrtf(fmaxf(2.0f * (e * y + 1.0f), 0.0f));
    } else {
        w = log1pf(y);
    }
#pragma unroll
    for (int it = 0; it < 12; ++it) {
        float ew  = expf(w);
        float f   = w * ew - y;
        float wp1 = w + 1.0f;
        float safe_wp1 = (fabsf(wp1) < 1e-6f) ? 1e-6f : wp1;
        float denom = ew * wp1 - (w + 2.0f) * f / (2.0f * safe_wp1);
        float safe_denom = (fabsf(denom) < 1e-30f) ? 1e-30f : denom;
        w = w - f / safe_denom;
    }
    return w;
}

__global__ __launch_bounds__(BLOCK) void superloss_kernel(
        const float* __restrict__ logits,
        const int*   __restrict__ targets,
        const float* __restrict__ cw,
        float*       __restrict__ out) {
    const int row = blockIdx.x;
    const float*  x  = logits + (size_t)row * C_CLASSES;
    const float4* x4 = (const float4*)x;   // rows are 128000 B -> 16B aligned

    // --- single-pass online max + sum(exp(x - max)) -------------------------
    float m = -INFINITY;
    float s = 0.0f;
#pragma unroll 4
    for (int j = threadIdx.x; j < C_CLASSES / 4; j += BLOCK) {
        float4 v = x4[j];
        float m4 = fmaxf(fmaxf(v.x, v.y), fmaxf(v.z, v.w));
        float mn = fmaxf(m, m4);
        s = s * expf(m - mn)
          + expf(v.x - mn) + expf(v.y - mn)
          + expf(v.z - mn) + expf(v.w - mn);
        m = mn;
    }

    // --- 64-lane butterfly reduce ------------------------------------------
#pragma unroll
    for (int off = 32; off > 0; off >>= 1) {
        float mo = __shfl_xor(m, off);
        float so = __shfl_xor(s, off);
        float mn = fmaxf(m, mo);
        s = s * expf(m - mn) + so * expf(mo - mn);
        m = mn;
    }

    // --- cross-wave combine (4 waves) --------------------------------------
    __shared__ float sm[4], ss[4];
    const int wid  = threadIdx.x >> 6;
    const int lane = threadIdx.x & 63;
    if (lane == 0) { sm[wid] = m; ss[wid] = s; }
    __syncthreads();

    if (threadIdx.x == 0) {
        float M = sm[0], S = ss[0];
#pragma unroll
        for (int k = 1; k < 4; ++k) {
            float mn = fmaxf(M, sm[k]);
            S = S * expf(M - mn) + ss[k] * expf(sm[k] - mn);
            M = mn;
        }
        const float lse = M + logf(S);

        const int   t   = targets[row];
        const float xt  = x[t];
        const float wt  = cw[t];
        const float nll = -(xt - lse) * wt;        // weighted CE, per sample

        // sigma_fn
        float y = 0.5f * fmaxf(kNEG2oE, nll - kTAU);   // LAM = 1
        y = fminf(fmaxf(y, -1.0f), 10.0f);
        const float sigma = expf(-lambertw0f(y));

        const float loss = (nll - kTAU) * sigma;
        atomicAdd(out, loss * (1.0f / (float)N_ROWS));
    }
}

extern "C" void kernel_launch(void* const* d_in, const int* in_sizes, int n_in,
                              void* d_out, int out_size, void* d_ws, size_t ws_size,
                              hipStream_t stream) {
    const float* logits  = (const float*)d_in[0];
    const int*   targets = (const int*)d_in[1];
    const float* cw      = (const float*)d_in[2];
    float*       out     = (float*)d_out;

    // d_out is re-poisoned 0xAA before every timed launch -> zero it on-stream.
    hipMemsetAsync(out, 0, sizeof(float), stream);

    superloss_kernel<<<N_ROWS, BLOCK, 0, stream>>>(logits, targets, cw, out);
}